// Round 10
// baseline (213.807 us; speedup 1.0000x reference)
//
#include <hip/hip_runtime.h>

#define N_NODES 50000
#define N_EDGES 800000
#define NB 196                 // buckets of 256 nodes: ceil(50000/256)
#define PBLOCKS 128            // partition blocks
#define CHUNK 6250             // N_EDGES / PBLOCKS (exact)
#define SCAN_N (NB * PBLOCKS)  // 25088
#define GEMM_BLOCKS 782        // ceil(50000/64)

typedef unsigned short ushort_t;

__device__ __forceinline__ float bflo(unsigned int u) {
    return __uint_as_float(u << 16);
}
__device__ __forceinline__ float bfhi(unsigned int u) {
    return __uint_as_float(u & 0xffff0000u);
}
__device__ __forceinline__ ushort_t f2bf(float f) {   // round-to-nearest-even
    unsigned int x = __float_as_uint(f);
    return (ushort_t)((x + 0x7fffu + ((x >> 16) & 1u)) >> 16);
}
__device__ __forceinline__ unsigned int pack_bf(float lo, float hi) {
    return (unsigned int)f2bf(lo) | ((unsigned int)f2bf(hi) << 16);
}

// ---------------- CSR build: atomic-free radix partition ----------------

__global__ __launch_bounds__(1024)
void part_scan(const int* __restrict__ blocktot, int* __restrict__ blockstart) {
    __shared__ int psum[1024];
    constexpr int PER = (SCAN_N + 1023) / 1024;   // 25
    const int t = threadIdx.x;
    const int base = t * PER;
    int local[PER];
    int s = 0;
#pragma unroll
    for (int i = 0; i < PER; ++i) {
        int idx = base + i;
        int v = (idx < SCAN_N) ? blocktot[idx] : 0;
        local[i] = s;
        s += v;
    }
    psum[t] = s;
    __syncthreads();
    for (int off = 1; off < 1024; off <<= 1) {
        int add = (t >= off) ? psum[t - off] : 0;
        __syncthreads();
        psum[t] += add;
        __syncthreads();
    }
    const int tbase = psum[t] - s;   // exclusive prefix of this thread
#pragma unroll
    for (int i = 0; i < PER; ++i) {
        int idx = base + i;
        if (idx < SCAN_N) blockstart[idx] = tbase + local[i];
    }
    if (t == 1023) blockstart[SCAN_N] = psum[1023];   // == N_EDGES
}

__global__ __launch_bounds__(256)
void part_write(const int* __restrict__ src, const int* __restrict__ dst,
                const int* __restrict__ blockstart, unsigned int* __restrict__ brec) {
    __shared__ int cur[NB];
    for (int i = threadIdx.x; i < NB; i += 256)
        cur[i] = blockstart[i * PBLOCKS + blockIdx.x];
    __syncthreads();
    const int e0 = blockIdx.x * CHUNK;
    const int e1 = e0 + CHUNK;
    for (int e = e0 + (int)threadIdx.x; e < e1; e += 256) {
        int d = dst[e];
        int s = src[e];
        int pos = atomicAdd(&cur[d >> 8], 1);
        brec[pos] = ((unsigned int)(d & 255) << 16) | (unsigned int)s;
    }
}

__global__ __launch_bounds__(256)
void bucket_fill(const int* __restrict__ blockstart,
                 const unsigned int* __restrict__ brec,
                 int* __restrict__ csr_src, int* __restrict__ row_ptr) {
    __shared__ int cnt[256];
    __shared__ int cur[256];
    const int b = blockIdx.x;
    const int node0 = b * 256;
    const int w0 = blockstart[b * PBLOCKS];
    const int w1 = blockstart[(b + 1) * PBLOCKS];
    const int t = threadIdx.x;
    cnt[t] = 0;
    __syncthreads();
    for (int i = w0 + t; i < w1; i += 256)
        atomicAdd(&cnt[brec[i] >> 16], 1);
    __syncthreads();
    const int v = cnt[t];
    cur[t] = v;
    __syncthreads();
    for (int off = 1; off < 256; off <<= 1) {
        int add = (t >= off) ? cur[t - off] : 0;
        __syncthreads();
        cur[t] += add;
        __syncthreads();
    }
    const int excl = cur[t] - v;
    const int node = node0 + t;
    if (node <= N_NODES) row_ptr[node] = w0 + excl;   // includes sentinel at node==N
    __syncthreads();
    cur[t] = w0 + excl;
    __syncthreads();
    for (int i = w0 + t; i < w1; i += 256) {
        unsigned int r = brec[i];
        int pos = atomicAdd(&cur[r >> 16], 1);
        csr_src[pos] = (int)(r & 0xffffu);
    }
}

// ---------------- Fused: layer-1 GEMM (782 blocks) + part_count (128 blocks) --------
// Outputs split into 32-col halves so each gather pass's table fits a 4MB XCD L2.
__global__ __launch_bounds__(256)
void gemm128_and_count(const float* __restrict__ A,
                       const float* __restrict__ B1,   // [64,64] Ws1
                       const float* __restrict__ B2,   // [64,64] Wn1
                       ushort_t* __restrict__ Sa,      // [N,32] self cols 0-31
                       ushort_t* __restrict__ Sb,      // [N,32] self cols 32-63
                       ushort_t* __restrict__ Na,      // [N,32] neigh cols 0-31
                       ushort_t* __restrict__ Nb,      // [N,32] neigh cols 32-63
                       const int* __restrict__ dst,
                       int* __restrict__ blocktot) {
    __shared__ __align__(16) char smem[50176];

    if (blockIdx.x >= GEMM_BLOCKS) {
        // ---- part_count ----
        int* hist = (int*)smem;
        const int pb = blockIdx.x - GEMM_BLOCKS;
        for (int i = threadIdx.x; i < NB; i += 256) hist[i] = 0;
        __syncthreads();
        const int e0 = pb * CHUNK;
        const int e1 = e0 + CHUNK;
        for (int e = e0 + (int)threadIdx.x; e < e1; e += 256)
            atomicAdd(&hist[dst[e] >> 8], 1);
        __syncthreads();
        for (int i = threadIdx.x; i < NB; i += 256)
            blocktot[i * PBLOCKS + pb] = hist[i];
        return;
    }

    // ---- gemm_cat<128> ----
    float (*As)[68]  = (float(*)[68])smem;              // 17408 B
    float (*Bs)[128] = (float(*)[128])(smem + 17408);   // 32768 B

    for (int i = threadIdx.x; i < 64 * 64; i += 256) {
        int k = i >> 6, j = i & 63;
        Bs[k][j]      = B1[i];
        Bs[k][j + 64] = B2[i];
    }
    const int m0 = blockIdx.x * 64;
    {
        int mloc = threadIdx.x >> 4;          // 0..15
        int k4   = (threadIdx.x & 15) * 4;    // 0..60
#pragma unroll
        for (int it = 0; it < 4; ++it) {
            int m  = mloc + it * 16;
            int gm = m0 + m;
            float4 a = (gm < N_NODES) ? *(const float4*)&A[(size_t)gm * 64 + k4]
                                      : make_float4(0.f, 0.f, 0.f, 0.f);
            As[k4 + 0][m] = a.x; As[k4 + 1][m] = a.y;
            As[k4 + 2][m] = a.z; As[k4 + 3][m] = a.w;
        }
    }
    __syncthreads();

    const int tm  = ((threadIdx.x >> 4) & 3) * 4 + (threadIdx.x >> 6) * 16;  // 0..60
    const int tn4 = (threadIdx.x & 15) * 4;                                   // 0..60

    float acc[4][2][4];
#pragma unroll
    for (int mi = 0; mi < 4; ++mi)
#pragma unroll
        for (int hh = 0; hh < 2; ++hh)
#pragma unroll
            for (int ni = 0; ni < 4; ++ni) acc[mi][hh][ni] = 0.f;

#pragma unroll 8
    for (int k = 0; k < 64; ++k) {
        float4 a  = *(const float4*)&As[k][tm];
        float4 b0 = *(const float4*)&Bs[k][tn4];
        float4 b1 = *(const float4*)&Bs[k][tn4 + 64];
        const float am[4] = {a.x, a.y, a.z, a.w};
#pragma unroll
        for (int mi = 0; mi < 4; ++mi) {
            acc[mi][0][0] += am[mi] * b0.x; acc[mi][0][1] += am[mi] * b0.y;
            acc[mi][0][2] += am[mi] * b0.z; acc[mi][0][3] += am[mi] * b0.w;
            acc[mi][1][0] += am[mi] * b1.x; acc[mi][1][1] += am[mi] * b1.y;
            acc[mi][1][2] += am[mi] * b1.z; acc[mi][1][3] += am[mi] * b1.w;
        }
    }

#pragma unroll
    for (int mi = 0; mi < 4; ++mi) {
        int gm = m0 + tm + mi;
        if (gm < N_NODES) {
            uint2 us, un;
            us.x = pack_bf(acc[mi][0][0], acc[mi][0][1]);
            us.y = pack_bf(acc[mi][0][2], acc[mi][0][3]);
            un.x = pack_bf(acc[mi][1][0], acc[mi][1][1]);
            un.y = pack_bf(acc[mi][1][2], acc[mi][1][3]);
            if (tn4 < 32) {
                *(uint2*)&Sa[(size_t)gm * 32 + tn4] = us;
                *(uint2*)&Na[(size_t)gm * 32 + tn4] = un;
            } else {
                *(uint2*)&Sb[(size_t)gm * 32 + tn4 - 32] = us;
                *(uint2*)&Nb[(size_t)gm * 32 + tn4 - 32] = un;
            }
        }
    }
}

// ---------------- Layer-2 GEMM: A is bf16 [N,64]; outputs 32-wide bf16 tables ------
__global__ __launch_bounds__(256)
void gemm_cat64_bf16(const ushort_t* __restrict__ A,
                     const float* __restrict__ B1,   // [64,32] Ws2
                     const float* __restrict__ B2,   // [64,32] Wn2
                     ushort_t* __restrict__ Cself,   // [N,32] bf16
                     ushort_t* __restrict__ Cn) {    // [N,32] bf16
    __shared__ float As[64][68];
    __shared__ float Bs[64][64];

    for (int i = threadIdx.x; i < 64 * 32; i += 256) {
        int k = i >> 5, j = i & 31;
        Bs[k][j]      = B1[i];
        Bs[k][j + 32] = B2[i];
    }
    const int m0 = blockIdx.x * 64;
    {
        int mloc = threadIdx.x >> 4;          // 0..15
        int k4   = (threadIdx.x & 15) * 4;    // 0..60
#pragma unroll
        for (int it = 0; it < 4; ++it) {
            int m  = mloc + it * 16;
            int gm = m0 + m;
            uint2 a = (gm < N_NODES) ? *(const uint2*)&A[(size_t)gm * 64 + k4]
                                     : make_uint2(0u, 0u);
            As[k4 + 0][m] = bflo(a.x); As[k4 + 1][m] = bfhi(a.x);
            As[k4 + 2][m] = bflo(a.y); As[k4 + 3][m] = bfhi(a.y);
        }
    }
    __syncthreads();

    const int tm  = ((threadIdx.x >> 4) & 3) * 4 + (threadIdx.x >> 6) * 16;  // 0..60
    const int tn4 = (threadIdx.x & 15) * 4;                                   // 0..60

    float acc[4][4];
#pragma unroll
    for (int mi = 0; mi < 4; ++mi)
#pragma unroll
        for (int ni = 0; ni < 4; ++ni) acc[mi][ni] = 0.f;

#pragma unroll 8
    for (int k = 0; k < 64; ++k) {
        float4 a = *(const float4*)&As[k][tm];
        float4 b = *(const float4*)&Bs[k][tn4];
        const float am[4] = {a.x, a.y, a.z, a.w};
#pragma unroll
        for (int mi = 0; mi < 4; ++mi) {
            acc[mi][0] += am[mi] * b.x; acc[mi][1] += am[mi] * b.y;
            acc[mi][2] += am[mi] * b.z; acc[mi][3] += am[mi] * b.w;
        }
    }

#pragma unroll
    for (int mi = 0; mi < 4; ++mi) {
        int gm = m0 + tm + mi;
        if (gm < N_NODES) {
            uint2 u;
            u.x = pack_bf(acc[mi][0], acc[mi][1]);
            u.y = pack_bf(acc[mi][2], acc[mi][3]);
            if (tn4 < 32) *(uint2*)&Cself[(size_t)gm * 32 + tn4] = u;
            else          *(uint2*)&Cn[(size_t)gm * 32 + (tn4 - 32)] = u;
        }
    }
}

// ---------------- 32-wide gather mean + fused epilogue ----------------
// Tables are [N,32] bf16 (3.2 MB -- fits per-XCD L2). One wave per node;
// 4 lanes/row (uint4 = 8 bf16 = 16 B each), R=16 rows in flight per tier.
// out[v, co:co+32] = act( Tself[v] + mean_{u in N(v)} Tn[u] + bias )
template <bool RELU, bool OBF16>
__global__ __launch_bounds__(256)
void gather32(const ushort_t* __restrict__ Tself,
              const ushort_t* __restrict__ Tn,
              const int* __restrict__ row_ptr,
              const int* __restrict__ csr_src,
              const float* __restrict__ bias,   // 32 floats (caller pre-offsets)
              void* __restrict__ outv, int out_stride, int out_co) {
    int v = (blockIdx.x * blockDim.x + threadIdx.x) >> 6;   // node id
    int lane = threadIdx.x & 63;
    int r = lane >> 2;           // 0..15 row group
    int c = lane & 3;            // handles cols c*8 .. c*8+7
    if (v >= N_NODES) return;
    int start = row_ptr[v];
    int cnt   = row_ptr[v + 1] - start;

    float a[8];
#pragma unroll
    for (int i = 0; i < 8; ++i) a[i] = 0.f;

#define ACC8(u)                                           \
    a[0] += bflo(u.x); a[1] += bfhi(u.x);                 \
    a[2] += bflo(u.y); a[3] += bfhi(u.y);                 \
    a[4] += bflo(u.z); a[5] += bfhi(u.z);                 \
    a[6] += bflo(u.w); a[7] += bfhi(u.w);

    int t = r;
    for (; t + 48 < cnt; t += 64) {   // 4-deep: 64 rows in flight per wave
        int s0 = csr_src[start + t];
        int s1 = csr_src[start + t + 16];
        int s2 = csr_src[start + t + 32];
        int s3 = csr_src[start + t + 48];
        uint4 u0 = *(const uint4*)&Tn[(size_t)s0 * 32 + c * 8];
        uint4 u1 = *(const uint4*)&Tn[(size_t)s1 * 32 + c * 8];
        uint4 u2 = *(const uint4*)&Tn[(size_t)s2 * 32 + c * 8];
        uint4 u3 = *(const uint4*)&Tn[(size_t)s3 * 32 + c * 8];
        ACC8(u0) ACC8(u1) ACC8(u2) ACC8(u3)
    }
    if (t + 16 < cnt) {
        int s0 = csr_src[start + t];
        int s1 = csr_src[start + t + 16];
        uint4 u0 = *(const uint4*)&Tn[(size_t)s0 * 32 + c * 8];
        uint4 u1 = *(const uint4*)&Tn[(size_t)s1 * 32 + c * 8];
        ACC8(u0) ACC8(u1)
        t += 32;
    }
    if (t < cnt) {
        int s = csr_src[start + t];
        uint4 u = *(const uint4*)&Tn[(size_t)s * 32 + c * 8];
        ACC8(u)
    }
#undef ACC8

#pragma unroll
    for (int off = 4; off < 64; off <<= 1) {
#pragma unroll
        for (int i = 0; i < 8; ++i) a[i] += __shfl_xor(a[i], off);
    }

    if (r == 0) {
        const float inv = 1.0f / (float)max(cnt, 1);
        uint4 su = *(const uint4*)&Tself[(size_t)v * 32 + c * 8];
        float4 bA = *(const float4*)&bias[c * 8];
        float4 bB = *(const float4*)&bias[c * 8 + 4];
        float o[8];
        o[0] = bflo(su.x) + a[0] * inv + bA.x;
        o[1] = bfhi(su.x) + a[1] * inv + bA.y;
        o[2] = bflo(su.y) + a[2] * inv + bA.z;
        o[3] = bfhi(su.y) + a[3] * inv + bA.w;
        o[4] = bflo(su.z) + a[4] * inv + bB.x;
        o[5] = bfhi(su.z) + a[5] * inv + bB.y;
        o[6] = bflo(su.w) + a[6] * inv + bB.z;
        o[7] = bfhi(su.w) + a[7] * inv + bB.w;
        if (RELU) {
#pragma unroll
            for (int i = 0; i < 8; ++i) o[i] = fmaxf(o[i], 0.f);
        }
        if (OBF16) {
            ushort_t* out = (ushort_t*)outv;
            uint4 p;
            p.x = pack_bf(o[0], o[1]); p.y = pack_bf(o[2], o[3]);
            p.z = pack_bf(o[4], o[5]); p.w = pack_bf(o[6], o[7]);
            *(uint4*)&out[(size_t)v * out_stride + out_co + c * 8] = p;
        } else {
            float* out = (float*)outv;
            *(float4*)&out[(size_t)v * out_stride + out_co + c * 8]     = make_float4(o[0], o[1], o[2], o[3]);
            *(float4*)&out[(size_t)v * out_stride + out_co + c * 8 + 4] = make_float4(o[4], o[5], o[6], o[7]);
        }
    }
}

extern "C" void kernel_launch(void* const* d_in, const int* in_sizes, int n_in,
                              void* d_out, int out_size, void* d_ws, size_t ws_size,
                              hipStream_t stream) {
    const float* features = (const float*)d_in[0];
    const float* W_self1  = (const float*)d_in[1];
    const float* W_neigh1 = (const float*)d_in[2];
    const float* b1       = (const float*)d_in[3];
    const float* W_self2  = (const float*)d_in[4];
    const float* W_neigh2 = (const float*)d_in[5];
    const float* b2       = (const float*)d_in[6];
    const int*   src      = (const int*)d_in[7];
    const int*   dst      = (const int*)d_in[8];

    // Workspace (no aliasing; ws is large):
    //   Sa,Sb,Na,Nb : N*32 bf16 each (3.2 MB each) -- layer-1 split tables
    //   h           : N*64 bf16 (6.4 MB)
    //   Tself2,Tn2  : N*32 bf16 each
    //   row_ptr: N+1; csr_src: E; brec: E; blocktot/blockstart: SCAN_N(+1)
    ushort_t* Sa = (ushort_t*)d_ws;
    ushort_t* Sb = Sa + (size_t)N_NODES * 32;
    ushort_t* Na = Sb + (size_t)N_NODES * 32;
    ushort_t* Nb = Na + (size_t)N_NODES * 32;
    ushort_t* h  = Nb + (size_t)N_NODES * 32;
    ushort_t* Tself2 = h + (size_t)N_NODES * 64;
    ushort_t* Tn2    = Tself2 + (size_t)N_NODES * 32;
    int* row_ptr     = (int*)(Tn2 + (size_t)N_NODES * 32);
    int* csr_src     = row_ptr + (N_NODES + 1);
    unsigned int* brec = (unsigned int*)(csr_src + N_EDGES);
    int* blocktot    = (int*)(brec + N_EDGES);
    int* blockstart  = blocktot + SCAN_N;

    const int gather_blocks = (N_NODES + 3) / 4;     // 12500 (4 waves/block)

    // ---- Overlapped: layer-1 GEMM + CSR part_count ----
    gemm128_and_count<<<GEMM_BLOCKS + PBLOCKS, 256, 0, stream>>>(
        features, W_self1, W_neigh1, Sa, Sb, Na, Nb, dst, blocktot);
    // ---- CSR build (by dst), atomic-free partition ----
    part_scan<<<1, 1024, 0, stream>>>(blocktot, blockstart);
    part_write<<<PBLOCKS, 256, 0, stream>>>(src, dst, blockstart, brec);
    bucket_fill<<<NB, 256, 0, stream>>>(blockstart, brec, csr_src, row_ptr);

    // ---- Layer 1 gather: two column passes, each with an L2-resident table ----
    gather32<true, true><<<gather_blocks, 256, 0, stream>>>(
        Sa, Na, row_ptr, csr_src, b1, h, 64, 0);
    gather32<true, true><<<gather_blocks, 256, 0, stream>>>(
        Sb, Nb, row_ptr, csr_src, b1 + 32, h, 64, 32);

    // ---- Layer 2 GEMM (bf16 A) ----
    gemm_cat64_bf16<<<GEMM_BLOCKS, 256, 0, stream>>>(h, W_self2, W_neigh2, Tself2, Tn2);

    // ---- Layer 2 gather + epilogue -> out (fp32) ----
    gather32<false, false><<<gather_blocks, 256, 0, stream>>>(
        Tself2, Tn2, row_ptr, csr_src, b2, d_out, 32, 0);
}

// Round 11
// 195.470 us; speedup vs baseline: 1.0938x; 1.0938x over previous
//
#include <hip/hip_runtime.h>

#define N_NODES 50000
#define N_EDGES 800000
#define NB 196                 // buckets of 256 nodes: ceil(50000/256)
#define PBLOCKS 128            // partition blocks
#define CHUNK 6250             // N_EDGES / PBLOCKS (exact)
#define SCAN_N (NB * PBLOCKS)  // 25088
#define GEMM_BLOCKS 782        // ceil(50000/64)

typedef unsigned short ushort_t;

__device__ __forceinline__ float bflo(unsigned int u) {
    return __uint_as_float(u << 16);
}
__device__ __forceinline__ float bfhi(unsigned int u) {
    return __uint_as_float(u & 0xffff0000u);
}
__device__ __forceinline__ ushort_t f2bf(float f) {   // round-to-nearest-even
    unsigned int x = __float_as_uint(f);
    return (ushort_t)((x + 0x7fffu + ((x >> 16) & 1u)) >> 16);
}
__device__ __forceinline__ unsigned int pack_bf(float lo, float hi) {
    return (unsigned int)f2bf(lo) | ((unsigned int)f2bf(hi) << 16);
}

// ---------------- CSR build: atomic-free radix partition ----------------

__global__ __launch_bounds__(1024)
void part_scan(const int* __restrict__ blocktot, int* __restrict__ blockstart) {
    __shared__ int psum[1024];
    constexpr int PER = (SCAN_N + 1023) / 1024;   // 25
    const int t = threadIdx.x;
    const int base = t * PER;
    int local[PER];
    int s = 0;
#pragma unroll
    for (int i = 0; i < PER; ++i) {
        int idx = base + i;
        int v = (idx < SCAN_N) ? blocktot[idx] : 0;
        local[i] = s;
        s += v;
    }
    psum[t] = s;
    __syncthreads();
    for (int off = 1; off < 1024; off <<= 1) {
        int add = (t >= off) ? psum[t - off] : 0;
        __syncthreads();
        psum[t] += add;
        __syncthreads();
    }
    const int tbase = psum[t] - s;   // exclusive prefix of this thread
#pragma unroll
    for (int i = 0; i < PER; ++i) {
        int idx = base + i;
        if (idx < SCAN_N) blockstart[idx] = tbase + local[i];
    }
    if (t == 1023) blockstart[SCAN_N] = psum[1023];   // == N_EDGES
}

__global__ __launch_bounds__(256)
void part_write(const int* __restrict__ src, const int* __restrict__ dst,
                const int* __restrict__ blockstart, unsigned int* __restrict__ brec) {
    __shared__ int cur[NB];
    for (int i = threadIdx.x; i < NB; i += 256)
        cur[i] = blockstart[i * PBLOCKS + blockIdx.x];
    __syncthreads();
    const int e0 = blockIdx.x * CHUNK;
    const int e1 = e0 + CHUNK;
    for (int e = e0 + (int)threadIdx.x; e < e1; e += 256) {
        int d = dst[e];
        int s = src[e];
        int pos = atomicAdd(&cur[d >> 8], 1);
        brec[pos] = ((unsigned int)(d & 255) << 16) | (unsigned int)s;
    }
}

__global__ __launch_bounds__(256)
void bucket_fill(const int* __restrict__ blockstart,
                 const unsigned int* __restrict__ brec,
                 int* __restrict__ csr_src, int* __restrict__ row_ptr) {
    __shared__ int cnt[256];
    __shared__ int cur[256];
    const int b = blockIdx.x;
    const int node0 = b * 256;
    const int w0 = blockstart[b * PBLOCKS];
    const int w1 = blockstart[(b + 1) * PBLOCKS];
    const int t = threadIdx.x;
    cnt[t] = 0;
    __syncthreads();
    for (int i = w0 + t; i < w1; i += 256)
        atomicAdd(&cnt[brec[i] >> 16], 1);
    __syncthreads();
    const int v = cnt[t];
    cur[t] = v;
    __syncthreads();
    for (int off = 1; off < 256; off <<= 1) {
        int add = (t >= off) ? cur[t - off] : 0;
        __syncthreads();
        cur[t] += add;
        __syncthreads();
    }
    const int excl = cur[t] - v;
    const int node = node0 + t;
    if (node <= N_NODES) row_ptr[node] = w0 + excl;   // includes sentinel at node==N
    __syncthreads();
    cur[t] = w0 + excl;
    __syncthreads();
    for (int i = w0 + t; i < w1; i += 256) {
        unsigned int r = brec[i];
        int pos = atomicAdd(&cur[r >> 16], 1);
        csr_src[pos] = (int)(r & 0xffffu);
    }
}

// ---------------- Fused: layer-1 GEMM (782 blocks) + part_count (128 blocks) --------
__global__ __launch_bounds__(256)
void gemm128_and_count(const float* __restrict__ A,
                       const float* __restrict__ B1,   // [64,64] Ws1
                       const float* __restrict__ B2,   // [64,64] Wn1
                       ushort_t* __restrict__ Cself,   // [N,64] bf16
                       ushort_t* __restrict__ Cn,      // [N,64] bf16
                       const int* __restrict__ dst,
                       int* __restrict__ blocktot) {
    __shared__ __align__(16) char smem[50176];

    if (blockIdx.x >= GEMM_BLOCKS) {
        // ---- part_count ----
        int* hist = (int*)smem;
        const int pb = blockIdx.x - GEMM_BLOCKS;
        for (int i = threadIdx.x; i < NB; i += 256) hist[i] = 0;
        __syncthreads();
        const int e0 = pb * CHUNK;
        const int e1 = e0 + CHUNK;
        for (int e = e0 + (int)threadIdx.x; e < e1; e += 256)
            atomicAdd(&hist[dst[e] >> 8], 1);
        __syncthreads();
        for (int i = threadIdx.x; i < NB; i += 256)
            blocktot[i * PBLOCKS + pb] = hist[i];
        return;
    }

    // ---- gemm_cat<128> ----
    float (*As)[68]  = (float(*)[68])smem;              // 17408 B
    float (*Bs)[128] = (float(*)[128])(smem + 17408);   // 32768 B

    for (int i = threadIdx.x; i < 64 * 64; i += 256) {
        int k = i >> 6, j = i & 63;
        Bs[k][j]      = B1[i];
        Bs[k][j + 64] = B2[i];
    }
    const int m0 = blockIdx.x * 64;
    {
        int mloc = threadIdx.x >> 4;          // 0..15
        int k4   = (threadIdx.x & 15) * 4;    // 0..60
#pragma unroll
        for (int it = 0; it < 4; ++it) {
            int m  = mloc + it * 16;
            int gm = m0 + m;
            float4 a = (gm < N_NODES) ? *(const float4*)&A[(size_t)gm * 64 + k4]
                                      : make_float4(0.f, 0.f, 0.f, 0.f);
            As[k4 + 0][m] = a.x; As[k4 + 1][m] = a.y;
            As[k4 + 2][m] = a.z; As[k4 + 3][m] = a.w;
        }
    }
    __syncthreads();

    const int tm  = ((threadIdx.x >> 4) & 3) * 4 + (threadIdx.x >> 6) * 16;  // 0..60
    const int tn4 = (threadIdx.x & 15) * 4;                                   // 0..60

    float acc[4][2][4];
#pragma unroll
    for (int mi = 0; mi < 4; ++mi)
#pragma unroll
        for (int hh = 0; hh < 2; ++hh)
#pragma unroll
            for (int ni = 0; ni < 4; ++ni) acc[mi][hh][ni] = 0.f;

#pragma unroll 8
    for (int k = 0; k < 64; ++k) {
        float4 a  = *(const float4*)&As[k][tm];
        float4 b0 = *(const float4*)&Bs[k][tn4];
        float4 b1 = *(const float4*)&Bs[k][tn4 + 64];
        const float am[4] = {a.x, a.y, a.z, a.w};
#pragma unroll
        for (int mi = 0; mi < 4; ++mi) {
            acc[mi][0][0] += am[mi] * b0.x; acc[mi][0][1] += am[mi] * b0.y;
            acc[mi][0][2] += am[mi] * b0.z; acc[mi][0][3] += am[mi] * b0.w;
            acc[mi][1][0] += am[mi] * b1.x; acc[mi][1][1] += am[mi] * b1.y;
            acc[mi][1][2] += am[mi] * b1.z; acc[mi][1][3] += am[mi] * b1.w;
        }
    }

#pragma unroll
    for (int mi = 0; mi < 4; ++mi) {
        int gm = m0 + tm + mi;
        if (gm < N_NODES) {
            uint2 us, un;
            us.x = pack_bf(acc[mi][0][0], acc[mi][0][1]);
            us.y = pack_bf(acc[mi][0][2], acc[mi][0][3]);
            un.x = pack_bf(acc[mi][1][0], acc[mi][1][1]);
            un.y = pack_bf(acc[mi][1][2], acc[mi][1][3]);
            *(uint2*)&Cself[(size_t)gm * 64 + tn4] = us;
            *(uint2*)&Cn[(size_t)gm * 64 + tn4]    = un;
        }
    }
}

// ---------------- Layer-2 GEMM: A is bf16 [N,64]; outputs bf16 tables ----------------
__global__ __launch_bounds__(256)
void gemm_cat64_bf16(const ushort_t* __restrict__ A,
                     const float* __restrict__ B1,   // [64,32] Ws2
                     const float* __restrict__ B2,   // [64,32] Wn2
                     ushort_t* __restrict__ Cself,   // [N,32] bf16
                     ushort_t* __restrict__ Cn) {    // [N,32] bf16
    __shared__ float As[64][68];
    __shared__ float Bs[64][64];

    for (int i = threadIdx.x; i < 64 * 32; i += 256) {
        int k = i >> 5, j = i & 31;
        Bs[k][j]      = B1[i];
        Bs[k][j + 32] = B2[i];
    }
    const int m0 = blockIdx.x * 64;
    {
        int mloc = threadIdx.x >> 4;          // 0..15
        int k4   = (threadIdx.x & 15) * 4;    // 0..60
#pragma unroll
        for (int it = 0; it < 4; ++it) {
            int m  = mloc + it * 16;
            int gm = m0 + m;
            uint2 a = (gm < N_NODES) ? *(const uint2*)&A[(size_t)gm * 64 + k4]
                                     : make_uint2(0u, 0u);
            As[k4 + 0][m] = bflo(a.x); As[k4 + 1][m] = bfhi(a.x);
            As[k4 + 2][m] = bflo(a.y); As[k4 + 3][m] = bfhi(a.y);
        }
    }
    __syncthreads();

    const int tm  = ((threadIdx.x >> 4) & 3) * 4 + (threadIdx.x >> 6) * 16;  // 0..60
    const int tn4 = (threadIdx.x & 15) * 4;                                   // 0..60

    float acc[4][4];
#pragma unroll
    for (int mi = 0; mi < 4; ++mi)
#pragma unroll
        for (int ni = 0; ni < 4; ++ni) acc[mi][ni] = 0.f;

#pragma unroll 8
    for (int k = 0; k < 64; ++k) {
        float4 a = *(const float4*)&As[k][tm];
        float4 b = *(const float4*)&Bs[k][tn4];
        const float am[4] = {a.x, a.y, a.z, a.w};
#pragma unroll
        for (int mi = 0; mi < 4; ++mi) {
            acc[mi][0] += am[mi] * b.x; acc[mi][1] += am[mi] * b.y;
            acc[mi][2] += am[mi] * b.z; acc[mi][3] += am[mi] * b.w;
        }
    }

#pragma unroll
    for (int mi = 0; mi < 4; ++mi) {
        int gm = m0 + tm + mi;
        if (gm < N_NODES) {
            uint2 u;
            u.x = pack_bf(acc[mi][0], acc[mi][1]);
            u.y = pack_bf(acc[mi][2], acc[mi][3]);
            if (tn4 < 32) *(uint2*)&Cself[(size_t)gm * 32 + tn4] = u;
            else          *(uint2*)&Cn[(size_t)gm * 32 + (tn4 - 32)] = u;
        }
    }
}

// ---------------- Gather mean (bf16 tables, 16 B/lane) + fused epilogue ----------------
// out[v] = act( Tself[v] + mean_{u in N(v)} Tn[u] + bias )
// One wave per node. LPR = F/8 lanes per row (uint4 = 8 bf16 = 16 B);
// R = 64/LPR rows in flight per tier. Index loads batched ahead of row loads
// in every tier so the wave keeps all its rows in flight on the latency chain.
template <int F, bool RELU, bool OBF16>
__global__ __launch_bounds__(256)
void gather_epilogue(const ushort_t* __restrict__ Tself,
                     const ushort_t* __restrict__ Tn,
                     const int* __restrict__ row_ptr,
                     const int* __restrict__ csr_src, const float* __restrict__ bias,
                     void* __restrict__ outv) {
    constexpr int LPR = F / 8;
    constexpr int R   = 64 / LPR;
    int v = (blockIdx.x * blockDim.x + threadIdx.x) >> 6;   // node id
    int lane = threadIdx.x & 63;
    int r = lane / LPR;
    int c = lane % LPR;          // handles cols c*8 .. c*8+7
    if (v >= N_NODES) return;
    int start = row_ptr[v];
    int cnt   = row_ptr[v + 1] - start;

    float a[8];
#pragma unroll
    for (int i = 0; i < 8; ++i) a[i] = 0.f;

#define ACC8(u)                                           \
    a[0] += bflo(u.x); a[1] += bfhi(u.x);                 \
    a[2] += bflo(u.y); a[3] += bfhi(u.y);                 \
    a[4] += bflo(u.z); a[5] += bfhi(u.z);                 \
    a[6] += bflo(u.w); a[7] += bfhi(u.w);

    int t = r;
    for (; t + 3 * R < cnt; t += 4 * R) {
        int s0 = csr_src[start + t];
        int s1 = csr_src[start + t + R];
        int s2 = csr_src[start + t + 2 * R];
        int s3 = csr_src[start + t + 3 * R];
        uint4 u0 = *(const uint4*)&Tn[(size_t)s0 * F + c * 8];
        uint4 u1 = *(const uint4*)&Tn[(size_t)s1 * F + c * 8];
        uint4 u2 = *(const uint4*)&Tn[(size_t)s2 * F + c * 8];
        uint4 u3 = *(const uint4*)&Tn[(size_t)s3 * F + c * 8];
        ACC8(u0) ACC8(u1) ACC8(u2) ACC8(u3)
    }
    if (t + R < cnt) {          // common case for mean degree 16 (R=8): one batch of 2
        int s0 = csr_src[start + t];
        int s1 = csr_src[start + t + R];
        uint4 u0 = *(const uint4*)&Tn[(size_t)s0 * F + c * 8];
        uint4 u1 = *(const uint4*)&Tn[(size_t)s1 * F + c * 8];
        ACC8(u0) ACC8(u1)
        t += 2 * R;
    }
    if (t < cnt) {
        int s = csr_src[start + t];
        uint4 u = *(const uint4*)&Tn[(size_t)s * F + c * 8];
        ACC8(u)
    }
#undef ACC8

#pragma unroll
    for (int off = LPR; off < 64; off <<= 1) {
#pragma unroll
        for (int i = 0; i < 8; ++i) a[i] += __shfl_xor(a[i], off);
    }

    if (r == 0) {
        const float inv = 1.0f / (float)max(cnt, 1);
        uint4 su = *(const uint4*)&Tself[(size_t)v * F + c * 8];
        float4 bA = *(const float4*)&bias[c * 8];
        float4 bB = *(const float4*)&bias[c * 8 + 4];
        float o[8];
        o[0] = bflo(su.x) + a[0] * inv + bA.x;
        o[1] = bfhi(su.x) + a[1] * inv + bA.y;
        o[2] = bflo(su.y) + a[2] * inv + bA.z;
        o[3] = bfhi(su.y) + a[3] * inv + bA.w;
        o[4] = bflo(su.z) + a[4] * inv + bB.x;
        o[5] = bfhi(su.z) + a[5] * inv + bB.y;
        o[6] = bflo(su.w) + a[6] * inv + bB.z;
        o[7] = bfhi(su.w) + a[7] * inv + bB.w;
        if (RELU) {
#pragma unroll
            for (int i = 0; i < 8; ++i) o[i] = fmaxf(o[i], 0.f);
        }
        if (OBF16) {
            ushort_t* out = (ushort_t*)outv;
            uint4 p;
            p.x = pack_bf(o[0], o[1]); p.y = pack_bf(o[2], o[3]);
            p.z = pack_bf(o[4], o[5]); p.w = pack_bf(o[6], o[7]);
            *(uint4*)&out[(size_t)v * F + c * 8] = p;
        } else {
            float* out = (float*)outv;
            *(float4*)&out[(size_t)v * F + c * 8]     = make_float4(o[0], o[1], o[2], o[3]);
            *(float4*)&out[(size_t)v * F + c * 8 + 4] = make_float4(o[4], o[5], o[6], o[7]);
        }
    }
}

extern "C" void kernel_launch(void* const* d_in, const int* in_sizes, int n_in,
                              void* d_out, int out_size, void* d_ws, size_t ws_size,
                              hipStream_t stream) {
    const float* features = (const float*)d_in[0];
    const float* W_self1  = (const float*)d_in[1];
    const float* W_neigh1 = (const float*)d_in[2];
    const float* b1       = (const float*)d_in[3];
    const float* W_self2  = (const float*)d_in[4];
    const float* W_neigh2 = (const float*)d_in[5];
    const float* b2       = (const float*)d_in[6];
    const int*   src      = (const int*)d_in[7];
    const int*   dst      = (const int*)d_in[8];

    // Workspace (all bf16 tables):
    //   Tself1 : N*64 bf16 (6.4 MB)  -- reused as Tself2+Tn2 (N*32 each) after gather1
    //   Tn1    : N*64 bf16 (6.4 MB)
    //   h      : N*64 bf16 (6.4 MB)
    //   row_ptr: N+1; csr_src: E; brec: E; blocktot/blockstart: SCAN_N(+1)
    ushort_t* Tself1 = (ushort_t*)d_ws;
    ushort_t* Tn1    = Tself1 + (size_t)N_NODES * 64;
    ushort_t* h      = Tn1 + (size_t)N_NODES * 64;
    int* row_ptr     = (int*)(h + (size_t)N_NODES * 64);
    int* csr_src     = row_ptr + (N_NODES + 1);
    unsigned int* brec = (unsigned int*)(csr_src + N_EDGES);
    int* blocktot    = (int*)(brec + N_EDGES);
    int* blockstart  = blocktot + SCAN_N;

    ushort_t* Tself2 = Tself1;                       // N*32, reuse (dead after gather1)
    ushort_t* Tn2    = Tself1 + (size_t)N_NODES * 32;

    const int gather_blocks = (N_NODES + 3) / 4;     // 12500 (4 waves/block)

    // ---- Overlapped: layer-1 GEMM + CSR part_count ----
    gemm128_and_count<<<GEMM_BLOCKS + PBLOCKS, 256, 0, stream>>>(
        features, W_self1, W_neigh1, Tself1, Tn1, dst, blocktot);
    // ---- CSR build (by dst), atomic-free partition ----
    part_scan<<<1, 1024, 0, stream>>>(blocktot, blockstart);
    part_write<<<PBLOCKS, 256, 0, stream>>>(src, dst, blockstart, brec);
    bucket_fill<<<NB, 256, 0, stream>>>(blockstart, brec, csr_src, row_ptr);

    // ---- Layer 1 gather + epilogue -> h (bf16) ----
    gather_epilogue<64, true, true><<<gather_blocks, 256, 0, stream>>>(
        Tself1, Tn1, row_ptr, csr_src, b1, h);

    // ---- Layer 2 GEMM (bf16 A) ----
    gemm_cat64_bf16<<<GEMM_BLOCKS, 256, 0, stream>>>(h, W_self2, W_neigh2, Tself2, Tn2);

    // ---- Layer 2 gather + epilogue -> out (fp32) ----
    gather_epilogue<32, false, false><<<gather_blocks, 256, 0, stream>>>(
        Tself2, Tn2, row_ptr, csr_src, b2, d_out);
}